// Round 2
// baseline (726.350 us; speedup 1.0000x reference)
//
#include <hip/hip_runtime.h>
#include <math.h>

#define C_   128
#define T_   64
#define V_   25
#define TV   1600       // T_*V_
#define CTV  204800     // C_*TV
#define EPS  1e-5f
#define HS   136        // hT/yT row stride in bf16 elements (272B = 17*16B)
#define ZS   29         // z row stride in floats (conflict-free b32)

typedef __bf16 bf16x8 __attribute__((ext_vector_type(8)));
typedef float  f32x4  __attribute__((ext_vector_type(4)));

// Pack conv weights into MFMA fragment order, bf16:
// frag f = (mt*4 + ks); element (lane l, j): A[o = mt*16 + (l&15)][c = ks*32 + (l>>4)*8 + j]
__global__ __launch_bounds__(256) void prep_pack(
    const float* __restrict__ W1, const float* __restrict__ W2,
    __bf16* __restrict__ W1p, __bf16* __restrict__ W2p) {
  int i = blockIdx.x * 256 + threadIdx.x;
  if (i < 32768) {   // W1: 16 mt * 4 ks * 64 * 8
    int j = i & 7, l = (i >> 3) & 63, ks = (i >> 9) & 3, mt = i >> 11;
    int o = mt * 16 + (l & 15);
    int c = ks * 32 + ((l >> 4) << 3) + j;
    W1p[i] = (__bf16)W1[o * 128 + c];
  }
  if (i < 16384) {   // W2: 8 mt * 4 ks * 64 * 8
    int j = i & 7, l = (i >> 3) & 63, ks = (i >> 9) & 3, mt = i >> 11;
    int o = mt * 16 + (l & 15);
    int c = ks * 32 + ((l >> 4) << 3) + j;
    W2p[i] = (__bf16)W2[o * 128 + c];
  }
}

__global__ __launch_bounds__(256, 4) void fused_mfma(
    const float* __restrict__ x,
    const float* __restrict__ bn0g, const float* __restrict__ bn0b,
    const float* __restrict__ bn0m, const float* __restrict__ bn0v,
    const float* __restrict__ b1,
    const float* __restrict__ bn1g, const float* __restrict__ bn1b,
    const float* __restrict__ bn1m, const float* __restrict__ bn1v,
    const float* __restrict__ bn2g, const float* __restrict__ bn2b,
    const float* __restrict__ bn2m, const float* __restrict__ bn2v,
    const float* __restrict__ topo, const float* __restrict__ spat,
    const float* __restrict__ b2,
    const __bf16* __restrict__ W1p, const __bf16* __restrict__ W2p,
    float* __restrict__ out) {
  __shared__ __bf16 sH[32 * HS];       // 8704 B: hT = BN0(x)^T, later yT
  __shared__ float  sZ1[128 * ZS];     // 14848 B
  __shared__ float  sZ2[128 * ZS];     // 14848 B
  __shared__ float  sInv[256], sAdd[256];  // BN1/BN2 folded params

  const int bt = blockIdx.x;           // 0..8191
  const int b  = bt >> 6;
  const int t  = bt & 63;
  const float* xs = x + (size_t)b * CTV + t * V_;
  float*       os = out + (size_t)b * CTV + t * V_;
  const int tid  = threadIdx.x;
  const int wave = tid >> 6, lane = tid & 63;
  const int lr = lane & 15, lg = lane >> 4;

  // ---------- phase 0: BN tables, zero pad rows, load x + BN0 -> sH[v][c] ----------
  {
    int o = tid;
    float g, bb, m, vv;
    if (o < 128) { g = bn1g[o]; bb = bn1b[o]; m = bn1m[o]; vv = bn1v[o]; }
    else { int c = o - 128; g = bn2g[c]; bb = bn2b[c]; m = bn2m[c]; vv = bn2v[c]; }
    float inv = g * rsqrtf(vv + EPS);
    sInv[o] = inv;
    sAdd[o] = fmaf(-m, inv, bb);
  }
  for (int i = tid; i < 7 * HS; i += 256) sH[25 * HS + i] = (__bf16)0.0f;
  {
    const int v = tid & 31, c0 = tid >> 5;
    if (v < V_) {
      for (int p = 0; p < 16; ++p) {
        int c = p * 8 + c0;
        float inv = bn0g[c] * rsqrtf(bn0v[c] + EPS);
        float add = fmaf(-bn0m[c], inv, bn0b[c]);
        sH[v * HS + c] = (__bf16)fmaf(xs[c * TV + v], inv, add);
      }
    }
  }
  __syncthreads();

  // ---------- phase 1: conv1 via MFMA (M=256,K=128,N=32pad), GELU, BN1/BN2 -> sZ ----------
  {
    f32x4 acc[4][2] = {};
    #pragma unroll
    for (int ks = 0; ks < 4; ++ks) {
      bf16x8 af[4];
      #pragma unroll
      for (int m4 = 0; m4 < 4; ++m4) {
        int frag = (wave * 4 + m4) * 4 + ks;
        af[m4] = *reinterpret_cast<const bf16x8*>(W1p + frag * 512 + lane * 8);
      }
      bf16x8 bfr[2];
      #pragma unroll
      for (int nt = 0; nt < 2; ++nt)
        bfr[nt] = *reinterpret_cast<const bf16x8*>(&sH[(nt * 16 + lr) * HS + ks * 32 + lg * 8]);
      #pragma unroll
      for (int m4 = 0; m4 < 4; ++m4)
        #pragma unroll
        for (int nt = 0; nt < 2; ++nt)
          acc[m4][nt] = __builtin_amdgcn_mfma_f32_16x16x32_bf16(af[m4], bfr[nt], acc[m4][nt], 0, 0, 0);
    }
    #pragma unroll
    for (int nt = 0; nt < 2; ++nt) {
      int v = nt * 16 + lr;
      if (v < V_) {
        #pragma unroll
        for (int m4 = 0; m4 < 4; ++m4) {
          int ob = wave * 64 + m4 * 16 + lg * 4;
          #pragma unroll
          for (int r = 0; r < 4; ++r) {
            int o = ob + r;
            float a = acc[m4][nt][r] + b1[o];
            float gel = 0.5f * a * (1.0f + erff(a * 0.70710678118654752440f));
            float z = fmaf(gel, sInv[o], sAdd[o]);
            if (o < 128) sZ1[o * ZS + v] = z;
            else         sZ2[(o - 128) * ZS + v] = z;
          }
        }
      }
    }
  }
  __syncthreads();

  // ---------- phase 2: spatial mixing (VALU f32) -> yT bf16 in sH ----------
  {
    const int c2 = tid & 127, hh = c2 >> 5, half = tid >> 7;
    const float* At  = topo + hh * 625;
    const float* Wsp = spat + hh * 625;
    float z1v[25], z2v[25];
    #pragma unroll
    for (int v = 0; v < 25; ++v) { z1v[v] = sZ1[c2 * ZS + v]; z2v[v] = sZ2[c2 * ZS + v]; }
    const int u0 = half ? 13 : 0;
    const int u1 = half ? 25 : 13;
    for (int u = u0; u < u1; ++u) {
      float ay = 0.f, aa = 0.f;
      #pragma unroll
      for (int v = 0; v < 25; ++v) {
        ay = fmaf(At[u * 25 + v],  z1v[v], ay);
        aa = fmaf(Wsp[u * 25 + v], z2v[v], aa);
      }
      // y = y1 + z1*attn   (z1[u] re-read from LDS: avoids runtime-indexed regs)
      sH[u * HS + c2] = (__bf16)fmaf(sZ1[c2 * ZS + u], aa, ay);
    }
  }
  __syncthreads();

  // ---------- phase 3: conv2 via MFMA (M=128,K=128,N=32pad) + residual + ReLU ----------
  {
    f32x4 acc[2][2] = {};
    #pragma unroll
    for (int ks = 0; ks < 4; ++ks) {
      bf16x8 af[2];
      #pragma unroll
      for (int m2 = 0; m2 < 2; ++m2) {
        int frag = (wave * 2 + m2) * 4 + ks;
        af[m2] = *reinterpret_cast<const bf16x8*>(W2p + frag * 512 + lane * 8);
      }
      bf16x8 bfr[2];
      #pragma unroll
      for (int nt = 0; nt < 2; ++nt)
        bfr[nt] = *reinterpret_cast<const bf16x8*>(&sH[(nt * 16 + lr) * HS + ks * 32 + lg * 8]);
      #pragma unroll
      for (int m2 = 0; m2 < 2; ++m2)
        #pragma unroll
        for (int nt = 0; nt < 2; ++nt)
          acc[m2][nt] = __builtin_amdgcn_mfma_f32_16x16x32_bf16(af[m2], bfr[nt], acc[m2][nt], 0, 0, 0);
    }
    #pragma unroll
    for (int nt = 0; nt < 2; ++nt) {
      int v = nt * 16 + lr;
      if (v < V_) {
        #pragma unroll
        for (int m2 = 0; m2 < 2; ++m2) {
          int ob = (wave * 2 + m2) * 16 + lg * 4;
          #pragma unroll
          for (int r = 0; r < 4; ++r) {
            int o = ob + r;
            float val = acc[m2][nt][r] + b2[o] + xs[o * TV + v];
            os[o * TV + v] = fmaxf(val, 0.0f);
          }
        }
      }
    }
  }
}

extern "C" void kernel_launch(void* const* d_in, const int* in_sizes, int n_in,
                              void* d_out, int out_size, void* d_ws, size_t ws_size,
                              hipStream_t stream) {
  const float* x    = (const float*)d_in[0];
  const float* bn0g = (const float*)d_in[1];
  const float* bn0b = (const float*)d_in[2];
  const float* bn0m = (const float*)d_in[3];
  const float* bn0v = (const float*)d_in[4];
  const float* W1   = (const float*)d_in[5];
  const float* b1   = (const float*)d_in[6];
  const float* bn1g = (const float*)d_in[7];
  const float* bn1b = (const float*)d_in[8];
  const float* bn1m = (const float*)d_in[9];
  const float* bn1v = (const float*)d_in[10];
  const float* bn2g = (const float*)d_in[11];
  const float* bn2b = (const float*)d_in[12];
  const float* bn2m = (const float*)d_in[13];
  const float* bn2v = (const float*)d_in[14];
  const float* topo = (const float*)d_in[15];
  const float* spat = (const float*)d_in[16];
  const float* W2   = (const float*)d_in[17];
  const float* b2   = (const float*)d_in[18];
  float* out = (float*)d_out;

  __bf16* W1p = (__bf16*)d_ws;            // 32768 elems = 64 KB
  __bf16* W2p = W1p + 32768;              // 16384 elems = 32 KB

  prep_pack<<<128, 256, 0, stream>>>(W1, W2, W1p, W2p);
  fused_mfma<<<8192, 256, 0, stream>>>(
      x, bn0g, bn0b, bn0m, bn0v, b1,
      bn1g, bn1b, bn1m, bn1v, bn2g, bn2b, bn2m, bn2v,
      topo, spat, b2, W1p, W2p, out);
}

// Round 3
// 237.794 us; speedup vs baseline: 3.0545x; 3.0545x over previous
//
#include <hip/hip_runtime.h>
#include <math.h>

#define C_   128
#define T_   64
#define V_   25
#define TV   1600       // T_*V_
#define CTV  204800     // C_*TV
#define EPS  1e-5f
#define TT   2          // t's per block
#define NC   64         // padded cols = TT*32
#define HS   136        // sM row stride (bf16), 272 B
#define ZS   72         // sZ row stride (bf16), 144 B (16B-aligned)

typedef __bf16 bf16x8 __attribute__((ext_vector_type(8)));
typedef float  f32x4  __attribute__((ext_vector_type(4)));

// Pack conv weights into MFMA A-fragment order, bf16:
// frag f = (mt*4 + ks); element (lane l, j): W[o = mt*16 + (l&15)][c = ks*32 + (l>>4)*8 + j]
__global__ __launch_bounds__(256) void prep_pack(
    const float* __restrict__ W1, const float* __restrict__ W2,
    __bf16* __restrict__ W1p, __bf16* __restrict__ W2p) {
  int i = blockIdx.x * 256 + threadIdx.x;
  if (i < 32768) {   // W1: 16 mt * 4 ks * 64 * 8
    int j = i & 7, l = (i >> 3) & 63, ks = (i >> 9) & 3, mt = i >> 11;
    int o = mt * 16 + (l & 15);
    int c = ks * 32 + ((l >> 4) << 3) + j;
    W1p[i] = (__bf16)W1[o * 128 + c];
  }
  if (i < 16384) {   // W2: 8 mt * 4 ks * 64 * 8
    int j = i & 7, l = (i >> 3) & 63, ks = (i >> 9) & 3, mt = i >> 11;
    int o = mt * 16 + (l & 15);
    int c = ks * 32 + ((l >> 4) << 3) + j;
    W2p[i] = (__bf16)W2[o * 128 + c];
  }
}

__global__ __launch_bounds__(512, 4) void fused_v3(
    const float* __restrict__ x,
    const float* __restrict__ bn0g, const float* __restrict__ bn0b,
    const float* __restrict__ bn0m, const float* __restrict__ bn0v,
    const float* __restrict__ b1,
    const float* __restrict__ bn1g, const float* __restrict__ bn1b,
    const float* __restrict__ bn1m, const float* __restrict__ bn1v,
    const float* __restrict__ bn2g, const float* __restrict__ bn2b,
    const float* __restrict__ bn2m, const float* __restrict__ bn2v,
    const float* __restrict__ topo, const float* __restrict__ spat,
    const float* __restrict__ b2,
    const __bf16* __restrict__ W1p, const __bf16* __restrict__ W2p,
    float* __restrict__ out) {
  __shared__ __bf16 sM[NC * HS];           // 17408 B: hT [col][c], later yT
  __shared__ __bf16 sZ1[C_ * ZS];          // 18432 B: z1 [c][col]
  __shared__ __bf16 sZ2[C_ * ZS];          // 18432 B: z2 [c][col]
  __shared__ float  sT[2 * 4 * 625];       // 20000 B: topo | spat
  __shared__ float  sInv[256], sAdd[256];  //  2048 B
  // total 76320 B -> 2 blocks/CU

  const int bt = blockIdx.x;               // 0..4095
  const int b  = bt >> 5;
  const int tb = bt & 31;                  // t-tile (TT t's each)
  const float* xb = x   + (size_t)b * CTV + tb * (TT * V_);
  float*       ob = out + (size_t)b * CTV + tb * (TT * V_);
  const int tid  = threadIdx.x;
  const int wave = tid >> 6, lane = tid & 63;
  const int lr = lane & 15, lg = lane >> 4;

  // ---------------- P0: tables, pad-zero, x load + BN0 -> sM[t*32+v][c] ----------------
  if (tid < 256) {
    int o = tid;
    float g, bb, m, vv;
    if (o < 128) { g = bn1g[o]; bb = bn1b[o]; m = bn1m[o]; vv = bn1v[o]; }
    else { int c = o - 128; g = bn2g[c]; bb = bn2b[c]; m = bn2m[c]; vv = bn2v[c]; }
    float inv = g * rsqrtf(vv + EPS);
    sInv[o] = inv;
    sAdd[o] = fmaf(-m, inv, bb);
  }
  for (int i = tid; i < 2500; i += 512) { sT[i] = topo[i]; sT[2500 + i] = spat[i]; }
  for (int i = tid; i < TT * 7 * HS; i += 512) {   // zero rows v=25..31 (both t)
    int rr = i / HS, cc = i - rr * HS;
    int t = rr / 7, v = 25 + (rr - t * 7);
    sM[(t * 32 + v) * HS + cc] = (__bf16)0.0f;
  }
  {
    const int c = tid >> 2, q = tid & 3;
    const int t = q & 1, vh = q >> 1;
    const int v0 = vh ? 13 : 0, v1 = vh ? 25 : 13;
    float inv = bn0g[c] * rsqrtf(bn0v[c] + EPS);
    float add = fmaf(-bn0m[c], inv, bn0b[c]);
    const float* xr = xb + c * TV + t * V_;
    for (int v = v0; v < v1; ++v)
      sM[(t * 32 + v) * HS + c] = (__bf16)fmaf(xr[v], inv, add);
  }
  __syncthreads();

  // ---------------- P1: conv1 MFMA (M=256,K=128,N=64), GELU, BN1/BN2 -> sZ1/sZ2 ----------------
  {
    f32x4 acc[2][4] = {};
    #pragma unroll
    for (int ks = 0; ks < 4; ++ks) {
      bf16x8 af[2];
      #pragma unroll
      for (int m2 = 0; m2 < 2; ++m2)
        af[m2] = *reinterpret_cast<const bf16x8*>(W1p + (((wave * 2 + m2) * 4 + ks) << 9) + lane * 8);
      bf16x8 bfr[4];
      #pragma unroll
      for (int n4 = 0; n4 < 4; ++n4)
        bfr[n4] = *reinterpret_cast<const bf16x8*>(&sM[(n4 * 16 + lr) * HS + ks * 32 + lg * 8]);
      #pragma unroll
      for (int m2 = 0; m2 < 2; ++m2)
        #pragma unroll
        for (int n4 = 0; n4 < 4; ++n4)
          acc[m2][n4] = __builtin_amdgcn_mfma_f32_16x16x32_bf16(af[m2], bfr[n4], acc[m2][n4], 0, 0, 0);
    }
    #pragma unroll
    for (int n4 = 0; n4 < 4; ++n4) {
      const int col = n4 * 16 + lr;
      const int v = col & 31;
      if (v < V_) {
        #pragma unroll
        for (int m2 = 0; m2 < 2; ++m2) {
          const int obase = (wave * 2 + m2) * 16 + lg * 4;
          #pragma unroll
          for (int r = 0; r < 4; ++r) {
            const int o = obase + r;
            float a = acc[m2][n4][r] + b1[o];
            float gel = 0.5f * a * (1.0f + erff(a * 0.70710678118654752440f));
            float z = fmaf(gel, sInv[o], sAdd[o]);
            if (o < 128) sZ1[o * ZS + col]         = (__bf16)z;
            else         sZ2[(o - 128) * ZS + col] = (__bf16)z;
          }
        }
      }
    }
  }
  __syncthreads();

  // ---------------- P2: spatial mixing (VALU) -> yT bf16 into sM ----------------
  {
    const int c = tid >> 2, t = (tid >> 1) & 1, uh = tid & 1;
    const int hh = c >> 5;
    const float* At  = sT + hh * 625;
    const float* Wsp = sT + 2500 + hh * 625;
    const __bf16* z1r = &sZ1[c * ZS + t * 32];
    const __bf16* z2r = &sZ2[c * ZS + t * 32];
    float z1v[25], z2v[25];
    {
      bf16x8 p0 = *reinterpret_cast<const bf16x8*>(z1r);
      bf16x8 p1 = *reinterpret_cast<const bf16x8*>(z1r + 8);
      bf16x8 p2 = *reinterpret_cast<const bf16x8*>(z1r + 16);
      #pragma unroll
      for (int j = 0; j < 8; ++j) { z1v[j] = (float)p0[j]; z1v[8 + j] = (float)p1[j]; }
      #pragma unroll
      for (int j = 0; j < 8; ++j) if (j < 8) { if (16 + j < 25) z1v[16 + j] = (float)p2[j]; }
      z1v[24] = (float)z1r[24];
      bf16x8 q0 = *reinterpret_cast<const bf16x8*>(z2r);
      bf16x8 q1 = *reinterpret_cast<const bf16x8*>(z2r + 8);
      bf16x8 q2 = *reinterpret_cast<const bf16x8*>(z2r + 16);
      #pragma unroll
      for (int j = 0; j < 8; ++j) { z2v[j] = (float)q0[j]; z2v[8 + j] = (float)q1[j]; }
      #pragma unroll
      for (int j = 0; j < 8; ++j) { if (16 + j < 25) z2v[16 + j] = (float)q2[j]; }
      z2v[24] = (float)z2r[24];
    }
    const int u0 = uh ? 13 : 0, u1 = uh ? 25 : 13;
    for (int u = u0; u < u1; ++u) {
      const float* ar = At + u * 25;
      const float* wr = Wsp + u * 25;
      float ay = 0.f, aa = 0.f;
      #pragma unroll
      for (int v = 0; v < 25; ++v) {
        ay = fmaf(ar[v], z1v[v], ay);
        aa = fmaf(wr[v], z2v[v], aa);
      }
      float z1u = (float)z1r[u];   // LDS re-read: avoids runtime-indexed reg array
      sM[(t * 32 + u) * HS + c] = (__bf16)fmaf(z1u, aa, ay);
    }
  }
  __syncthreads();

  // ---------------- P3: conv2 MFMA (M=128,K=128,N=64) + residual + ReLU -> global ----------------
  {
    f32x4 acc[4] = {};
    #pragma unroll
    for (int ks = 0; ks < 4; ++ks) {
      bf16x8 af = *reinterpret_cast<const bf16x8*>(W2p + (((wave) * 4 + ks) << 9) + lane * 8);
      #pragma unroll
      for (int n4 = 0; n4 < 4; ++n4) {
        bf16x8 bfr = *reinterpret_cast<const bf16x8*>(&sM[(n4 * 16 + lr) * HS + ks * 32 + lg * 8]);
        acc[n4] = __builtin_amdgcn_mfma_f32_16x16x32_bf16(af, bfr, acc[n4], 0, 0, 0);
      }
    }
    #pragma unroll
    for (int n4 = 0; n4 < 4; ++n4) {
      const int col = n4 * 16 + lr;
      const int u = col & 31, t = col >> 5;
      if (u < V_) {
        #pragma unroll
        for (int r = 0; r < 4; ++r) {
          const int o = wave * 16 + lg * 4 + r;
          const int off = o * TV + t * V_ + u;
          float val = acc[n4][r] + b2[o] + xb[off];
          ob[off] = fmaxf(val, 0.0f);
        }
      }
    }
  }
}

extern "C" void kernel_launch(void* const* d_in, const int* in_sizes, int n_in,
                              void* d_out, int out_size, void* d_ws, size_t ws_size,
                              hipStream_t stream) {
  const float* x    = (const float*)d_in[0];
  const float* bn0g = (const float*)d_in[1];
  const float* bn0b = (const float*)d_in[2];
  const float* bn0m = (const float*)d_in[3];
  const float* bn0v = (const float*)d_in[4];
  const float* W1   = (const float*)d_in[5];
  const float* b1   = (const float*)d_in[6];
  const float* bn1g = (const float*)d_in[7];
  const float* bn1b = (const float*)d_in[8];
  const float* bn1m = (const float*)d_in[9];
  const float* bn1v = (const float*)d_in[10];
  const float* bn2g = (const float*)d_in[11];
  const float* bn2b = (const float*)d_in[12];
  const float* bn2m = (const float*)d_in[13];
  const float* bn2v = (const float*)d_in[14];
  const float* topo = (const float*)d_in[15];
  const float* spat = (const float*)d_in[16];
  const float* W2   = (const float*)d_in[17];
  const float* b2   = (const float*)d_in[18];
  float* out = (float*)d_out;

  __bf16* W1p = (__bf16*)d_ws;            // 32768 elems = 64 KB
  __bf16* W2p = W1p + 32768;              // 16384 elems = 32 KB

  prep_pack<<<128, 256, 0, stream>>>(W1, W2, W1p, W2p);
  fused_v3<<<4096, 512, 0, stream>>>(
      x, bn0g, bn0b, bn0m, bn0v, b1,
      bn1g, bn1b, bn1m, bn1v, bn2g, bn2b, bn2m, bn2v,
      topo, spat, b2, W1p, W2p, out);
}

// Round 4
// 115.453 us; speedup vs baseline: 6.2913x; 2.0597x over previous
//
#include <hip/hip_runtime.h>
#include <math.h>

#define C_   128
#define T_   64
#define V_   25
#define TV   1600       // T_*V_
#define CTV  204800     // C_*TV
#define EPS  1e-5f
#define TT   2          // t's per block
#define NC   64         // padded cols = TT*32
#define HS   136        // sM row stride (bf16), 272 B (16B-aligned)
#define ZS   72         // sZ row stride (bf16), 144 B (16B-aligned)

typedef __bf16 bf16x8 __attribute__((ext_vector_type(8)));
typedef float  f32x4  __attribute__((ext_vector_type(4)));

// Exact-enough GELU: erf via Abramowitz-Stegun 7.1.26 (|eps| < 2.5e-7).
// s = 1 - erf(y), y = |x|/sqrt(2);  x>=0: gelu = x - 0.5*x*s ; x<0: 0.5*x*s
__device__ __forceinline__ float gelu_exact(float x) {
  float y = fabsf(x) * 0.70710678118654752440f;
  float t = __builtin_amdgcn_rcpf(fmaf(0.3275911f, y, 1.0f));
  float p = fmaf(1.061405429f, t, -1.453152027f);
  p = fmaf(p, t, 1.421413741f);
  p = fmaf(p, t, -0.284496736f);
  p = fmaf(p, t, 0.254829592f);
  p = p * t;
  float s = p * __expf(-y * y);
  float hxs = 0.5f * x * s;
  return x >= 0.0f ? x - hxs : hxs;
}

// Pack conv weights + spatial matrices into MFMA A-fragment order (bf16).
// A-frag: lane l, elem j -> A[row = l&15][k = (l>>4)*8 + j]
__global__ __launch_bounds__(256) void prep_pack(
    const float* __restrict__ W1, const float* __restrict__ W2,
    const float* __restrict__ topo, const float* __restrict__ spat,
    __bf16* __restrict__ W1p, __bf16* __restrict__ W2p, __bf16* __restrict__ Sp) {
  int i = blockIdx.x * 256 + threadIdx.x;
  if (i < 32768) {   // W1: 16 mt * 4 ks * 64 * 8
    int j = i & 7, l = (i >> 3) & 63, ks = (i >> 9) & 3, mt = i >> 11;
    int o = mt * 16 + (l & 15);
    int c = ks * 32 + ((l >> 4) << 3) + j;
    W1p[i] = (__bf16)W1[o * 128 + c];
  }
  if (i < 16384) {   // W2: 8 mt * 4 ks * 64 * 8
    int j = i & 7, l = (i >> 3) & 63, ks = (i >> 9) & 3, mt = i >> 11;
    int o = mt * 16 + (l & 15);
    int c = ks * 32 + ((l >> 4) << 3) + j;
    W2p[i] = (__bf16)W2[o * 128 + c];
  }
  if (i < 8192) {    // Sp: h(2) * mat(2) * mt(2) * 64 * 8, zero-padded u,v>=25
    int j = i & 7, l = (i >> 3) & 63, mt = (i >> 9) & 1, mat = (i >> 10) & 1, h = i >> 11;
    int u = mt * 16 + (l & 15);
    int v = ((l >> 4) << 3) + j;
    const float* src = mat ? spat : topo;
    Sp[i] = (__bf16)((u < 25 && v < 25) ? src[h * 625 + u * 25 + v] : 0.0f);
  }
}

__global__ __launch_bounds__(512, 4) void fused_v4(
    const float* __restrict__ x,
    const float* __restrict__ bn0g, const float* __restrict__ bn0b,
    const float* __restrict__ bn0m, const float* __restrict__ bn0v,
    const float* __restrict__ b1,
    const float* __restrict__ bn1g, const float* __restrict__ bn1b,
    const float* __restrict__ bn1m, const float* __restrict__ bn1v,
    const float* __restrict__ bn2g, const float* __restrict__ bn2b,
    const float* __restrict__ bn2m, const float* __restrict__ bn2v,
    const float* __restrict__ b2,
    const __bf16* __restrict__ W1p, const __bf16* __restrict__ W2p,
    const __bf16* __restrict__ Sp,
    float* __restrict__ out) {
  __shared__ __bf16 sM[NC * HS];           // 17408 B: hT [col][c], later yT
  __shared__ __bf16 sZ1[C_ * ZS];          // 18432 B: z1 [c][t*32+v]
  __shared__ __bf16 sZ2[C_ * ZS];          // 18432 B: z2 [c][t*32+v]
  __shared__ float  sInv[256], sAdd[256];  // BN1/BN2 folded
  __shared__ float  sB1[256], sB2[128];
  // total 57856 B -> 2 blocks/CU

  const int bt = blockIdx.x;               // 0..4095
  const int b  = bt >> 5;
  const int tb = bt & 31;
  const float* xb = x   + (size_t)b * CTV + tb * (TT * V_);
  float*       ob = out + (size_t)b * CTV + tb * (TT * V_);
  const int tid  = threadIdx.x;
  const int wave = tid >> 6, lane = tid & 63;
  const int lr = lane & 15, lg = lane >> 4;

  // hoist spatial A-frag loads (global, independent of LDS; hides under P0/P1)
  const int h2 = wave >> 1, ch = wave & 1;
  bf16x8 at[2], as2[2];
  #pragma unroll
  for (int mt = 0; mt < 2; ++mt) {
    at[mt]  = *reinterpret_cast<const bf16x8*>(Sp + (((h2 * 2 + 0) * 2 + mt) << 9) + lane * 8);
    as2[mt] = *reinterpret_cast<const bf16x8*>(Sp + (((h2 * 2 + 1) * 2 + mt) << 9) + lane * 8);
  }

  // ---------------- P0: tables, zero sZ pad cols, x load + BN0 -> sM[t*32+v][c] ----------------
  if (tid < 256) {
    int o = tid;
    float g, bb, m, vv;
    if (o < 128) { g = bn1g[o]; bb = bn1b[o]; m = bn1m[o]; vv = bn1v[o]; }
    else { int c = o - 128; g = bn2g[c]; bb = bn2b[c]; m = bn2m[c]; vv = bn2v[c]; }
    float inv = g * rsqrtf(vv + EPS);
    sInv[o] = inv;
    sAdd[o] = fmaf(-m, inv, bb);
    sB1[o] = b1[o];
    if (o < 128) sB2[o] = b2[o];
  }
  {  // zero v in [24,32) of both z buffers (v=24 rewritten by P1; pads must be 0 for P2 MFMA)
    int buf = tid >> 8, c = (tid >> 1) & 127, t = tid & 1;
    bf16x8 zz = {};
    *reinterpret_cast<bf16x8*>((buf ? sZ2 : sZ1) + c * ZS + t * 32 + 24) = zz;
  }
  {
    const int c = tid >> 2, q = tid & 3;
    const int t = q & 1, vh = q >> 1;
    const int v0 = vh ? 13 : 0, v1 = vh ? 25 : 13;
    float inv = bn0g[c] * rsqrtf(bn0v[c] + EPS);
    float add = fmaf(-bn0m[c], inv, bn0b[c]);
    const float* xr = xb + c * TV + t * V_;
    for (int v = v0; v < v1; ++v)
      sM[(t * 32 + v) * HS + c] = (__bf16)fmaf(xr[v], inv, add);
  }
  __syncthreads();

  // ---------------- P1: conv1 MFMA (M=256,K=128,N=64), GELU, BN1/BN2 -> sZ1/sZ2 ----------------
  {
    f32x4 acc[2][4] = {};
    #pragma unroll
    for (int ks = 0; ks < 4; ++ks) {
      bf16x8 af[2];
      #pragma unroll
      for (int m2 = 0; m2 < 2; ++m2)
        af[m2] = *reinterpret_cast<const bf16x8*>(W1p + (((wave * 2 + m2) * 4 + ks) << 9) + lane * 8);
      bf16x8 bfr[4];
      #pragma unroll
      for (int n4 = 0; n4 < 4; ++n4)
        bfr[n4] = *reinterpret_cast<const bf16x8*>(&sM[(n4 * 16 + lr) * HS + ks * 32 + lg * 8]);
      #pragma unroll
      for (int m2 = 0; m2 < 2; ++m2)
        #pragma unroll
        for (int n4 = 0; n4 < 4; ++n4)
          acc[m2][n4] = __builtin_amdgcn_mfma_f32_16x16x32_bf16(af[m2], bfr[n4], acc[m2][n4], 0, 0, 0);
    }
    #pragma unroll
    for (int n4 = 0; n4 < 4; ++n4) {
      const int col = n4 * 16 + lr;
      const int v = col & 31;
      if (v < V_) {
        #pragma unroll
        for (int m2 = 0; m2 < 2; ++m2) {
          const int obase = (wave * 2 + m2) * 16 + lg * 4;
          #pragma unroll
          for (int r = 0; r < 4; ++r) {
            const int o = obase + r;
            float a = acc[m2][n4][r] + sB1[o];
            float z = fmaf(gelu_exact(a), sInv[o], sAdd[o]);
            if (o < 128) sZ1[o * ZS + col]         = (__bf16)z;
            else         sZ2[(o - 128) * ZS + col] = (__bf16)z;
          }
        }
      }
    }
  }
  __syncthreads();

  // ---------------- P2: spatial mixing via MFMA -> yT bf16 into sM ----------------
  {
    // wave = h2*2 + ch: head h2, c-half ch (16 c's), both t's.
    const int cbase = h2 * 32 + ch * 16;
    f32x4 accY[2][2] = {}, accA[2][2] = {};   // [mt][t]
    #pragma unroll
    for (int t = 0; t < 2; ++t) {
      bf16x8 bz1 = *reinterpret_cast<const bf16x8*>(&sZ1[(cbase + lr) * ZS + t * 32 + lg * 8]);
      bf16x8 bz2 = *reinterpret_cast<const bf16x8*>(&sZ2[(cbase + lr) * ZS + t * 32 + lg * 8]);
      #pragma unroll
      for (int mt = 0; mt < 2; ++mt) {
        accY[mt][t] = __builtin_amdgcn_mfma_f32_16x16x32_bf16(at[mt],  bz1, accY[mt][t], 0, 0, 0);
        accA[mt][t] = __builtin_amdgcn_mfma_f32_16x16x32_bf16(as2[mt], bz2, accA[mt][t], 0, 0, 0);
      }
    }
    const int c = cbase + lr;
    #pragma unroll
    for (int mt = 0; mt < 2; ++mt) {
      #pragma unroll
      for (int t = 0; t < 2; ++t) {
        #pragma unroll
        for (int r = 0; r < 4; ++r) {
          const int u = mt * 16 + lg * 4 + r;
          if (u < V_) {
            float z1u = (float)sZ1[c * ZS + t * 32 + u];
            float yv = fmaf(z1u, accA[mt][t][r], accY[mt][t][r]);
            sM[(t * 32 + u) * HS + c] = (__bf16)yv;
          }
        }
      }
    }
  }
  __syncthreads();

  // ---------------- P3: conv2 MFMA (M=128,K=128,N=64) + residual + ReLU -> global ----------------
  {
    f32x4 acc[4] = {};
    #pragma unroll
    for (int ks = 0; ks < 4; ++ks) {
      bf16x8 af = *reinterpret_cast<const bf16x8*>(W2p + ((wave * 4 + ks) << 9) + lane * 8);
      #pragma unroll
      for (int n4 = 0; n4 < 4; ++n4) {
        bf16x8 bfr = *reinterpret_cast<const bf16x8*>(&sM[(n4 * 16 + lr) * HS + ks * 32 + lg * 8]);
        acc[n4] = __builtin_amdgcn_mfma_f32_16x16x32_bf16(af, bfr, acc[n4], 0, 0, 0);
      }
    }
    #pragma unroll
    for (int n4 = 0; n4 < 4; ++n4) {
      const int col = n4 * 16 + lr;
      const int u = col & 31, t = col >> 5;
      if (u < V_) {
        #pragma unroll
        for (int r = 0; r < 4; ++r) {
          const int o = wave * 16 + lg * 4 + r;
          const int off = o * TV + t * V_ + u;
          float val = acc[n4][r] + sB2[o] + xb[off];
          ob[off] = fmaxf(val, 0.0f);
        }
      }
    }
  }
}

extern "C" void kernel_launch(void* const* d_in, const int* in_sizes, int n_in,
                              void* d_out, int out_size, void* d_ws, size_t ws_size,
                              hipStream_t stream) {
  const float* x    = (const float*)d_in[0];
  const float* bn0g = (const float*)d_in[1];
  const float* bn0b = (const float*)d_in[2];
  const float* bn0m = (const float*)d_in[3];
  const float* bn0v = (const float*)d_in[4];
  const float* W1   = (const float*)d_in[5];
  const float* b1   = (const float*)d_in[6];
  const float* bn1g = (const float*)d_in[7];
  const float* bn1b = (const float*)d_in[8];
  const float* bn1m = (const float*)d_in[9];
  const float* bn1v = (const float*)d_in[10];
  const float* bn2g = (const float*)d_in[11];
  const float* bn2b = (const float*)d_in[12];
  const float* bn2m = (const float*)d_in[13];
  const float* bn2v = (const float*)d_in[14];
  const float* topo = (const float*)d_in[15];
  const float* spat = (const float*)d_in[16];
  const float* W2   = (const float*)d_in[17];
  const float* b2   = (const float*)d_in[18];
  float* out = (float*)d_out;

  __bf16* W1p = (__bf16*)d_ws;            // 32768 elems
  __bf16* W2p = W1p + 32768;              // 16384 elems
  __bf16* Sp  = W2p + 16384;              //  8192 elems (total 114688 B)

  prep_pack<<<128, 256, 0, stream>>>(W1, W2, topo, spat, W1p, W2p, Sp);
  fused_v4<<<4096, 512, 0, stream>>>(
      x, bn0g, bn0b, bn0m, bn0v, b1,
      bn1g, bn1b, bn1m, bn1v, bn2g, bn2b, bn2m, bn2v,
      b2, W1p, W2p, Sp, out);
}